// Round 7
// baseline (37.817 us; speedup 1.0000x reference)
//
#include <hip/hip_runtime.h>

// Masked scatter-add: out[index[i]] += rate[i] where starttime[i] <= t < endtime[i].
//
// R1: direct global atomics -> 250-way memory-side contention, 113 us.
// R2: LDS hist + partials + parallel reduce: 45 us.
// R3: plain-store reduce (8 workgroups) latency-bound at 118 us.
// R4: parallel reduce restored -> 36.5 us. Hist occupancy 18%, HBM 19%.
// R5: 1024-thr blocks -> occupancy 72%, no change. TLP not the constraint.
// R6: batched-ILP conditional loads -> no change (37.1 us). ILP not it either.
// R7: A/B on the remaining invariant: the conditional dependent-load chain
//     (wait s/e -> branch -> issue idx/rate -> wait). Timed replays are fully
//     L3-resident (FETCH ~4 MB), so conditional loads save bytes that are FREE
//     warm while costing a serial latency hop every iteration. Load all four
//     arrays unconditionally: 8 independent dwordx4 in flight, one wait/iter,
//     zero data-dependent branches in the load path.

#define MAX_BINS 2048   // problem SIZE = 2000; static LDS must be compile-time
#define HIST_BLOCK 1024

__global__ void __launch_bounds__(HIST_BLOCK)
hist_partial_kernel(const int* __restrict__ index,
                    const float* __restrict__ rate,
                    const float* __restrict__ starttime,
                    const float* __restrict__ endtime,
                    const float* __restrict__ t_ptr,
                    float* __restrict__ ws,   // [gridDim.x][size] partials
                    int n, int size)
{
    __shared__ float hist[MAX_BINS];
    for (int j = threadIdx.x; j < size; j += blockDim.x) hist[j] = 0.0f;
    __syncthreads();

    const float t = t_ptr[0];
    const int tid      = blockIdx.x * blockDim.x + threadIdx.x;
    const int nthreads = gridDim.x * blockDim.x;
    const int nvec     = n >> 2;

    const int4*   idx4v = reinterpret_cast<const int4*>(index);
    const float4* rat4v = reinterpret_cast<const float4*>(rate);
    const float4* st4v  = reinterpret_cast<const float4*>(starttime);
    const float4* en4v  = reinterpret_cast<const float4*>(endtime);

    int i = tid;

    // Main: 2 points/iter, ALL 8 loads unconditional and independent ->
    // back-to-back issue, single vmcnt drain, no branches before the loads.
    for (; i + nthreads < nvec; i += 2 * nthreads) {
        const int ib = i + nthreads;

        const float4 sA = st4v[i];  const float4 eA = en4v[i];
        const int4   iA = idx4v[i]; const float4 rA = rat4v[i];
        const float4 sB = st4v[ib];  const float4 eB = en4v[ib];
        const int4   iB = idx4v[ib]; const float4 rB = rat4v[ib];

        if ((sA.x <= t) & (t < eA.x)) atomicAdd(&hist[iA.x], rA.x);  // ds_add_f32
        if ((sA.y <= t) & (t < eA.y)) atomicAdd(&hist[iA.y], rA.y);
        if ((sA.z <= t) & (t < eA.z)) atomicAdd(&hist[iA.z], rA.z);
        if ((sA.w <= t) & (t < eA.w)) atomicAdd(&hist[iA.w], rA.w);

        if ((sB.x <= t) & (t < eB.x)) atomicAdd(&hist[iB.x], rB.x);
        if ((sB.y <= t) & (t < eB.y)) atomicAdd(&hist[iB.y], rB.y);
        if ((sB.z <= t) & (t < eB.z)) atomicAdd(&hist[iB.z], rB.z);
        if ((sB.w <= t) & (t < eB.w)) atomicAdd(&hist[iB.w], rB.w);
    }

    // Remainder chunk-point (at most one stride left).
    for (; i < nvec; i += nthreads) {
        const float4 s4 = st4v[i];  const float4 e4 = en4v[i];
        const int4   i4 = idx4v[i]; const float4 r4 = rat4v[i];
        if ((s4.x <= t) & (t < e4.x)) atomicAdd(&hist[i4.x], r4.x);
        if ((s4.y <= t) & (t < e4.y)) atomicAdd(&hist[i4.y], r4.y);
        if ((s4.z <= t) & (t < e4.z)) atomicAdd(&hist[i4.z], r4.z);
        if ((s4.w <= t) & (t < e4.w)) atomicAdd(&hist[i4.w], r4.w);
    }

    // Element tail (N % 4) — N=10M divisible by 4, but stay generic.
    for (int k = (nvec << 2) + tid; k < n; k += nthreads) {
        if (starttime[k] <= t && t < endtime[k]) atomicAdd(&hist[index[k]], rate[k]);
    }

    __syncthreads();

    // Coalesced, vectorized flush of this block's private partial row.
    float* part = ws + (size_t)blockIdx.x * size;
    const int nq = size >> 2;
    float4* part4 = reinterpret_cast<float4*>(part);
    const float4* hist4 = reinterpret_cast<const float4*>(hist);
    for (int j = threadIdx.x; j < nq; j += blockDim.x) part4[j] = hist4[j];
    for (int j = (nq << 2) + threadIdx.x; j < size; j += blockDim.x) part[j] = hist[j];
}

// Parallel over partials: block (x=j-tile, y=b-chunk). Each thread sums its
// chunk (coalesced: lanes read consecutive j at fixed b) then ONE atomicAdd.
// gridDim.y-way contention per bin -- negligible.
__global__ void __launch_bounds__(256)
reduce_partials_kernel(const float* __restrict__ ws,
                       float* __restrict__ out,
                       int npart, int size)
{
    const int j = blockIdx.x * blockDim.x + threadIdx.x;
    if (j >= size) return;

    const int chunk  = npart / gridDim.y;
    const int bstart = blockIdx.y * chunk;
    const int bend   = (blockIdx.y == gridDim.y - 1) ? npart : bstart + chunk;

    float sum = 0.0f;
    int b = bstart;
    #pragma unroll 8
    for (; b + 8 <= bend; b += 8) {
        sum += ws[(size_t)(b + 0) * size + j];
        sum += ws[(size_t)(b + 1) * size + j];
        sum += ws[(size_t)(b + 2) * size + j];
        sum += ws[(size_t)(b + 3) * size + j];
        sum += ws[(size_t)(b + 4) * size + j];
        sum += ws[(size_t)(b + 5) * size + j];
        sum += ws[(size_t)(b + 6) * size + j];
        sum += ws[(size_t)(b + 7) * size + j];
    }
    for (; b < bend; ++b) sum += ws[(size_t)b * size + j];

    atomicAdd(&out[j], sum);
}

// Fallback (ws too small / size too large): direct predicated global atomics.
__global__ void __launch_bounds__(256)
direct_atomic_kernel(const int* __restrict__ index,
                     const float* __restrict__ rate,
                     const float* __restrict__ starttime,
                     const float* __restrict__ endtime,
                     const float* __restrict__ t_ptr,
                     float* __restrict__ out, int n)
{
    const float t = t_ptr[0];
    const int tid      = blockIdx.x * blockDim.x + threadIdx.x;
    const int nthreads = gridDim.x * blockDim.x;
    for (int i = tid; i < n; i += nthreads) {
        if (starttime[i] <= t && t < endtime[i]) atomicAdd(&out[index[i]], rate[i]);
    }
}

extern "C" void kernel_launch(void* const* d_in, const int* in_sizes, int n_in,
                              void* d_out, int out_size, void* d_ws, size_t ws_size,
                              hipStream_t stream)
{
    const int*   index     = (const int*)  d_in[0];
    const float* rate      = (const float*)d_in[1];
    const float* starttime = (const float*)d_in[2];
    const float* endtime   = (const float*)d_in[3];
    const float* t_ptr     = (const float*)d_in[4];

    float* out = (float*)d_out;
    float* ws  = (float*)d_ws;
    const int n    = in_sizes[0];
    const int size = out_size;

    // Atomic reduce accumulates into d_out -> zero it every call (replays are
    // not re-poisoned by the harness).
    hipMemsetAsync(out, 0, (size_t)size * sizeof(float), stream);

    // npart=512 partial rows (4 MB traffic); 1024 threads/block:
    // 16 waves x 2 blocks/CU = 32 waves/CU.
    int npart = (int)(ws_size / ((size_t)size * sizeof(float)));
    if (npart > 512) npart = 512;

    if (size <= MAX_BINS && npart >= 64) {
        hist_partial_kernel<<<npart, HIST_BLOCK, 0, stream>>>(
            index, rate, starttime, endtime, t_ptr, ws, n, size);

        dim3 g2((size + 255) / 256, 16);   // 128 blocks, 32 loads/thread
        reduce_partials_kernel<<<g2, 256, 0, stream>>>(ws, out, npart, size);
    } else {
        int grid = (n + 255) / 256;
        if (grid > 2048) grid = 2048;
        direct_atomic_kernel<<<grid, 256, 0, stream>>>(
            index, rate, starttime, endtime, t_ptr, out, n);
    }
}

// Round 8
// 31.522 us; speedup vs baseline: 1.1997x; 1.1997x over previous
//
#include <hip/hip_runtime.h>

// Masked scatter-add: out[index[i]] += rate[i] where starttime[i] <= t < endtime[i].
//
// R1: direct global atomics -> 250-way memory-side contention, 113 us.
// R2: LDS hist + partials + parallel reduce: 45 us.
// R3: plain-store reduce (8 workgroups) latency-bound at 118 us.
// R4: parallel reduce restored -> 36.5 us.
// R5: occupancy 18%->72%: no change. TLP not the constraint.
// R6: batched-ILP: no change. ILP not the constraint.
// R7: branch-free unconditional loads: no change (37.8). Dependent-load-chain
//     theory refuted. Effective hist rate ~5.3 TB/s on a 160 MB mandatory
//     stream == ~85% of the 6.3 TB/s streaming ceiling (L3 fabric ~= HBM
//     class). The stream is done; only aux overhead is recoverable.
// R8: 2 dispatches instead of 3: out-zeroing folded into hist (block 0 zeroes
//     out before reduce runs -- stream order guarantees safety), npart 512->256
//     (partials RT 8->4 MB, reduce loads halved).

#define MAX_BINS 2048   // problem SIZE = 2000; static LDS must be compile-time
#define HIST_BLOCK 1024

__global__ void __launch_bounds__(HIST_BLOCK)
hist_partial_kernel(const int* __restrict__ index,
                    const float* __restrict__ rate,
                    const float* __restrict__ starttime,
                    const float* __restrict__ endtime,
                    const float* __restrict__ t_ptr,
                    float* __restrict__ ws,   // [gridDim.x][size] partials
                    float* __restrict__ out,  // zeroed here (block 0) for the reduce
                    int n, int size)
{
    __shared__ float hist[MAX_BINS];
    for (int j = threadIdx.x; j < size; j += blockDim.x) hist[j] = 0.0f;

    // Fold the d_out memset into this kernel: reduce_partials runs after us in
    // stream order, so zeroing here is race-free. Saves one dispatch.
    if (blockIdx.x == 0) {
        for (int j = threadIdx.x; j < size; j += blockDim.x) out[j] = 0.0f;
    }
    __syncthreads();

    const float t = t_ptr[0];
    const int tid      = blockIdx.x * blockDim.x + threadIdx.x;
    const int nthreads = gridDim.x * blockDim.x;
    const int nvec     = n >> 2;

    const int4*   idx4v = reinterpret_cast<const int4*>(index);
    const float4* rat4v = reinterpret_cast<const float4*>(rate);
    const float4* st4v  = reinterpret_cast<const float4*>(starttime);
    const float4* en4v  = reinterpret_cast<const float4*>(endtime);

    int i = tid;

    // 2 points/iter, all 8 loads unconditional and independent -> back-to-back
    // issue, single vmcnt drain, no data-dependent branches in the load path.
    for (; i + nthreads < nvec; i += 2 * nthreads) {
        const int ib = i + nthreads;

        const float4 sA = st4v[i];  const float4 eA = en4v[i];
        const int4   iA = idx4v[i]; const float4 rA = rat4v[i];
        const float4 sB = st4v[ib];  const float4 eB = en4v[ib];
        const int4   iB = idx4v[ib]; const float4 rB = rat4v[ib];

        if ((sA.x <= t) & (t < eA.x)) atomicAdd(&hist[iA.x], rA.x);  // ds_add_f32
        if ((sA.y <= t) & (t < eA.y)) atomicAdd(&hist[iA.y], rA.y);
        if ((sA.z <= t) & (t < eA.z)) atomicAdd(&hist[iA.z], rA.z);
        if ((sA.w <= t) & (t < eA.w)) atomicAdd(&hist[iA.w], rA.w);

        if ((sB.x <= t) & (t < eB.x)) atomicAdd(&hist[iB.x], rB.x);
        if ((sB.y <= t) & (t < eB.y)) atomicAdd(&hist[iB.y], rB.y);
        if ((sB.z <= t) & (t < eB.z)) atomicAdd(&hist[iB.z], rB.z);
        if ((sB.w <= t) & (t < eB.w)) atomicAdd(&hist[iB.w], rB.w);
    }

    // Remainder chunk-point (at most one stride left).
    for (; i < nvec; i += nthreads) {
        const float4 s4 = st4v[i];  const float4 e4 = en4v[i];
        const int4   i4 = idx4v[i]; const float4 r4 = rat4v[i];
        if ((s4.x <= t) & (t < e4.x)) atomicAdd(&hist[i4.x], r4.x);
        if ((s4.y <= t) & (t < e4.y)) atomicAdd(&hist[i4.y], r4.y);
        if ((s4.z <= t) & (t < e4.z)) atomicAdd(&hist[i4.z], r4.z);
        if ((s4.w <= t) & (t < e4.w)) atomicAdd(&hist[i4.w], r4.w);
    }

    // Element tail (N % 4) — N=10M divisible by 4, but stay generic.
    for (int k = (nvec << 2) + tid; k < n; k += nthreads) {
        if (starttime[k] <= t && t < endtime[k]) atomicAdd(&hist[index[k]], rate[k]);
    }

    __syncthreads();

    // Coalesced, vectorized flush of this block's private partial row.
    float* part = ws + (size_t)blockIdx.x * size;
    const int nq = size >> 2;
    float4* part4 = reinterpret_cast<float4*>(part);
    const float4* hist4 = reinterpret_cast<const float4*>(hist);
    for (int j = threadIdx.x; j < nq; j += blockDim.x) part4[j] = hist4[j];
    for (int j = (nq << 2) + threadIdx.x; j < size; j += blockDim.x) part[j] = hist[j];
}

// Parallel over partials: block (x=j-tile, y=b-chunk). Each thread sums its
// chunk (coalesced: lanes read consecutive j at fixed b) then ONE atomicAdd.
// gridDim.y-way contention per bin -- negligible.
__global__ void __launch_bounds__(256)
reduce_partials_kernel(const float* __restrict__ ws,
                       float* __restrict__ out,
                       int npart, int size)
{
    const int j = blockIdx.x * blockDim.x + threadIdx.x;
    if (j >= size) return;

    const int chunk  = npart / gridDim.y;
    const int bstart = blockIdx.y * chunk;
    const int bend   = (blockIdx.y == gridDim.y - 1) ? npart : bstart + chunk;

    float sum = 0.0f;
    int b = bstart;
    #pragma unroll 8
    for (; b + 8 <= bend; b += 8) {
        sum += ws[(size_t)(b + 0) * size + j];
        sum += ws[(size_t)(b + 1) * size + j];
        sum += ws[(size_t)(b + 2) * size + j];
        sum += ws[(size_t)(b + 3) * size + j];
        sum += ws[(size_t)(b + 4) * size + j];
        sum += ws[(size_t)(b + 5) * size + j];
        sum += ws[(size_t)(b + 6) * size + j];
        sum += ws[(size_t)(b + 7) * size + j];
    }
    for (; b < bend; ++b) sum += ws[(size_t)b * size + j];

    atomicAdd(&out[j], sum);
}

// Fallback (ws too small / size too large): direct predicated global atomics.
__global__ void __launch_bounds__(256)
direct_atomic_kernel(const int* __restrict__ index,
                     const float* __restrict__ rate,
                     const float* __restrict__ starttime,
                     const float* __restrict__ endtime,
                     const float* __restrict__ t_ptr,
                     float* __restrict__ out, int n)
{
    const float t = t_ptr[0];
    const int tid      = blockIdx.x * blockDim.x + threadIdx.x;
    const int nthreads = gridDim.x * blockDim.x;
    for (int i = tid; i < n; i += nthreads) {
        if (starttime[i] <= t && t < endtime[i]) atomicAdd(&out[index[i]], rate[i]);
    }
}

extern "C" void kernel_launch(void* const* d_in, const int* in_sizes, int n_in,
                              void* d_out, int out_size, void* d_ws, size_t ws_size,
                              hipStream_t stream)
{
    const int*   index     = (const int*)  d_in[0];
    const float* rate      = (const float*)d_in[1];
    const float* starttime = (const float*)d_in[2];
    const float* endtime   = (const float*)d_in[3];
    const float* t_ptr     = (const float*)d_in[4];

    float* out = (float*)d_out;
    float* ws  = (float*)d_ws;
    const int n    = in_sizes[0];
    const int size = out_size;

    // npart=256: 1 block/CU (16 waves/CU -- R4/R5 showed >=8 waves/CU is
    // BW-equivalent), partial RT down to 4 MB total.
    int npart = (int)(ws_size / ((size_t)size * sizeof(float)));
    if (npart > 256) npart = 256;

    if (size <= MAX_BINS && npart >= 64) {
        hist_partial_kernel<<<npart, HIST_BLOCK, 0, stream>>>(
            index, rate, starttime, endtime, t_ptr, ws, out, n, size);

        dim3 g2((size + 255) / 256, 16);   // 128 blocks, 16 loads/thread
        reduce_partials_kernel<<<g2, 256, 0, stream>>>(ws, out, npart, size);
    } else {
        hipMemsetAsync(out, 0, (size_t)size * sizeof(float), stream);
        int grid = (n + 255) / 256;
        if (grid > 2048) grid = 2048;
        direct_atomic_kernel<<<grid, 256, 0, stream>>>(
            index, rate, starttime, endtime, t_ptr, out, n);
    }
}